// Round 2
// baseline (519.327 us; speedup 1.0000x reference)
//
#include <hip/hip_runtime.h>
#include <stdint.h>
#include <stddef.h>

#define NN 8192      // nodes
#define KD 256       // in_dim
#define CD 256       // out_dim*heads
#define FD 128       // out_dim
#define BI 32        // i-tile rows per block (k_gat)
#define BJ 64        // j-tile

typedef __attribute__((ext_vector_type(4))) float f32x4;
typedef __attribute__((ext_vector_type(8))) short b16x8;

__device__ __forceinline__ unsigned short f2bf(float x) {
    unsigned int u = __float_as_uint(x);
    u += 0x7fffu + ((u >> 16) & 1u);
    return (unsigned short)(u >> 16);
}

// ---------------------------------------------------------------------------
// Kernel 1: T = feat @ W.T (bf16 MFMA) fused with:
//   - scores s[h][n], d[h][n] (head-major) from fp32 accumulators
//   - FRAGMENT-MAJOR bf16 output Tt: element (c,n) stored at
//       ((c>>4)*(NN/8) + (n>>3))*128 + (c&15)*8 + (n&7)
//     so a k_gat B-fragment load (16 lanes x 16B) is contiguous per quad.
// grid=128, block=256
// ---------------------------------------------------------------------------
__global__ __launch_bounds__(256) void k_transform(
    const float* __restrict__ feat, const float* __restrict__ W,
    const float* __restrict__ asrc, const float* __restrict__ adst,
    unsigned short* __restrict__ Tt, float* __restrict__ s, float* __restrict__ d)
{
    __shared__ unsigned short a_lds[64 * 32];    // 4KB
    __shared__ unsigned short b_lds[256 * 32];   // 16KB
    __shared__ unsigned short tr_lds[256 * 72];  // 36KB
    __shared__ float sc_lds[4][64];              // 1KB
    __shared__ float dc_lds[4][64];              // 1KB

    const int t = threadIdx.x;
    const int wave = t >> 6, lane = t & 63;
    const int l15 = lane & 15, quad = lane >> 4;
    const int n0 = blockIdx.x * 64;
    const int ai = t >> 2, ag = t & 3;

    f32x4 acc[4][4] = {};
    for (int kc = 0; kc < 8; ++kc) {
        const int k0 = kc * 32;
        __syncthreads();
        { // stage A: features[n0+ai][k0 + ag*8 .. +7] -> bf16
            const float* src = feat + (size_t)(n0 + ai) * KD + k0 + ag * 8;
            const float4 v0 = *(const float4*)src;
            const float4 v1 = *(const float4*)(src + 4);
            union { unsigned short us[8]; b16x8 v; } pk;
            pk.us[0] = f2bf(v0.x); pk.us[1] = f2bf(v0.y);
            pk.us[2] = f2bf(v0.z); pk.us[3] = f2bf(v0.w);
            pk.us[4] = f2bf(v1.x); pk.us[5] = f2bf(v1.y);
            pk.us[6] = f2bf(v1.z); pk.us[7] = f2bf(v1.w);
            const int slot = ag ^ ((ai >> 1) & 3);
            *(b16x8*)&a_lds[ai * 32 + slot * 8] = pk.v;
        }
        for (int p = 0; p < 4; ++p) { // stage B: W[c][k0 + g*8 .. +7]
            const int G = p * 256 + t;
            const int c = G >> 2, g = G & 3;
            const float* src = W + (size_t)c * KD + k0 + g * 8;
            const float4 v0 = *(const float4*)src;
            const float4 v1 = *(const float4*)(src + 4);
            union { unsigned short us[8]; b16x8 v; } pk;
            pk.us[0] = f2bf(v0.x); pk.us[1] = f2bf(v0.y);
            pk.us[2] = f2bf(v0.z); pk.us[3] = f2bf(v0.w);
            pk.us[4] = f2bf(v1.x); pk.us[5] = f2bf(v1.y);
            pk.us[6] = f2bf(v1.z); pk.us[7] = f2bf(v1.w);
            const int slot = g ^ ((c >> 1) & 3);
            *(b16x8*)&b_lds[c * 32 + slot * 8] = pk.v;
        }
        __syncthreads();
        b16x8 af[4], bfr[4];
        for (int mt = 0; mt < 4; ++mt) {
            const int m = mt * 16 + l15;
            af[mt] = *(const b16x8*)&a_lds[m * 32 + (quad ^ ((m >> 1) & 3)) * 8];
        }
        for (int nt = 0; nt < 4; ++nt) {
            const int c = wave * 64 + nt * 16 + l15;
            bfr[nt] = *(const b16x8*)&b_lds[c * 32 + (quad ^ ((c >> 1) & 3)) * 8];
        }
        for (int mt = 0; mt < 4; ++mt)
            for (int nt = 0; nt < 4; ++nt)
                acc[mt][nt] = __builtin_amdgcn_mfma_f32_16x16x32_bf16(
                    af[mt], bfr[nt], acc[mt][nt], 0, 0, 0);
    }

    // ---- epilogue: scores (fp32) + fragment-major bf16 store ----
    float aS[4], aD[4];
    for (int nt = 0; nt < 4; ++nt) {
        const int c = wave * 64 + nt * 16 + l15;
        aS[nt] = asrc[c]; aD[nt] = adst[c];
    }
    for (int mt = 0; mt < 4; ++mt)
        for (int r = 0; r < 4; ++r) {
            float vs = 0.f, vd = 0.f;
            for (int nt = 0; nt < 4; ++nt) {
                const float x = acc[mt][nt][r];
                vs += x * aS[nt]; vd += x * aD[nt];
            }
            vs += __shfl_xor(vs, 1); vd += __shfl_xor(vd, 1);
            vs += __shfl_xor(vs, 2); vd += __shfl_xor(vd, 2);
            vs += __shfl_xor(vs, 4); vd += __shfl_xor(vd, 4);
            vs += __shfl_xor(vs, 8); vd += __shfl_xor(vd, 8);
            if (l15 == 0) {
                const int nl = mt * 16 + quad * 4 + r;
                sc_lds[wave][nl] = vs; dc_lds[wave][nl] = vd;
            }
        }
    for (int mt = 0; mt < 4; ++mt)
        for (int nt = 0; nt < 4; ++nt)
            for (int r = 0; r < 4; ++r) {
                const int c = wave * 64 + nt * 16 + l15;
                const int n = mt * 16 + quad * 4 + r;
                tr_lds[c * 72 + n] = f2bf(acc[mt][nt][r]);
            }
    __syncthreads();
    if (t < 128) {
        const int n = t >> 1, h = t & 1;
        s[(size_t)h * NN + n0 + n] = sc_lds[h * 2][n] + sc_lds[h * 2 + 1][n];
        d[(size_t)h * NN + n0 + n] = dc_lds[h * 2][n] + dc_lds[h * 2 + 1][n];
    }
    // fragment-major store: granule (c, g) -> 16B at
    //   ((c>>4)*(NN/8) + (n0/8+g))*128 + (c&15)*8
    for (int p = 0; p < 8; ++p) {
        const int idx = p * 256 + t;       // 2048 granules
        const int c = idx >> 3, g = idx & 7;
        const size_t q = (size_t)(n0 >> 3) + g;
        unsigned short* dst = Tt + (((size_t)(c >> 4) * (NN >> 3) + q) * 16 + (c & 15)) * 8;
        *(b16x8*)dst = *(const b16x8*)&tr_lds[c * 72 + g * 8];
    }
}

// ---------------------------------------------------------------------------
// Kernel 2 (v3): fused masked-softmax aggregation — ZERO LDS, ZERO barriers.
//   block=256 = 4 fully-independent waves: wave = (head h, 16-row group grp).
//   Each lane computes its OWN A-fragment elements (exp weights) in-register:
//     A row  = l15  -> i = i0 + grp*16 + l15
//     A k    = quad*8+e (ks*32 offset per K-half)
//   B fragments load lane-contiguous from fragment-major Tt.
//   Adjacency (HBM stream) register-prefetched one j-tile ahead.
// ---------------------------------------------------------------------------
__global__ __launch_bounds__(256) void k_gat(
    const int* __restrict__ adj, const unsigned short* __restrict__ Tt,
    const float* __restrict__ s, const float* __restrict__ d,
    float* __restrict__ num_part,   // [jsplit][NN][CD]
    float* __restrict__ den_part,   // [jsplit][2][NN]
    int jchunk)
{
    const int t = threadIdx.x;
    const int wave = t >> 6, lane = t & 63;
    const int l15 = lane & 15, quad = lane >> 4;
    const int h = wave >> 1, grp = wave & 1;

    // XCD chunk-affinity (bijective for gridDim.y in {2,4})
    const int flat = blockIdx.y * gridDim.x + blockIdx.x;
    const int xcd = flat & 7, o = flat >> 3;
    const int xpc = 8 / gridDim.y;
    const int chunk = xcd / xpc;
    const int ib = (xcd % xpc) * (gridDim.x / xpc) + o;
    const int i0 = ib * BI;
    const int jbase = chunk * jchunk;

    const int irow = i0 + grp * 16 + l15;       // this lane's A-row
    const float sreg = s[(size_t)h * NN + irow];
    const float* dh = d + (size_t)h * NN;
    const int njt = jchunk / BJ;

    f32x4 acc[8] = {};
    float denl = 0.f;

    const int* arowp = adj + (size_t)irow * NN;
    // prefetch iter-0 adjacency (2 int4 per K-half)
    int4 aC0, aC1, aC2, aC3;
    aC0 = *(const int4*)(arowp + jbase + quad * 8);
    aC1 = *(const int4*)(arowp + jbase + quad * 8 + 4);
    aC2 = *(const int4*)(arowp + jbase + 32 + quad * 8);
    aC3 = *(const int4*)(arowp + jbase + 32 + quad * 8 + 4);

    for (int jt = 0; jt < njt; ++jt) {
        const int j0 = jbase + jt * BJ;
        const int qbase = j0 >> 3;
        // B fragments: lane-contiguous (quad-groups of 16 lanes x 16B)
        b16x8 bfr[2][8];
        for (int ks = 0; ks < 2; ++ks)
            for (int nt = 0; nt < 8; ++nt) {
                const int g = h * 8 + nt;
                const size_t e = ((size_t)g * (NN >> 3) + qbase + ks * 4 + quad) * 128
                               + l15 * 8;
                bfr[ks][nt] = *(const b16x8*)(Tt + e);
            }
        // d scores (L2-hot, head-major -> contiguous float4s)
        const float4 dv0a = *(const float4*)(dh + j0 + quad * 8);
        const float4 dv0b = *(const float4*)(dh + j0 + quad * 8 + 4);
        const float4 dv1a = *(const float4*)(dh + j0 + 32 + quad * 8);
        const float4 dv1b = *(const float4*)(dh + j0 + 32 + quad * 8 + 4);
        // prefetch next-iter adjacency (clamped; tail value unused)
        const int jn = (jt + 1 < njt) ? j0 + BJ : jbase;
        int4 aP0 = *(const int4*)(arowp + jn + quad * 8);
        int4 aP1 = *(const int4*)(arowp + jn + quad * 8 + 4);
        int4 aP2 = *(const int4*)(arowp + jn + 32 + quad * 8);
        int4 aP3 = *(const int4*)(arowp + jn + 32 + quad * 8 + 4);
        // exp(leaky)·mask -> in-register A fragments
        const int   am0[8] = {aC0.x, aC0.y, aC0.z, aC0.w, aC1.x, aC1.y, aC1.z, aC1.w};
        const int   am1[8] = {aC2.x, aC2.y, aC2.z, aC2.w, aC3.x, aC3.y, aC3.z, aC3.w};
        const float dv0[8] = {dv0a.x, dv0a.y, dv0a.z, dv0a.w, dv0b.x, dv0b.y, dv0b.z, dv0b.w};
        const float dv1[8] = {dv1a.x, dv1a.y, dv1a.z, dv1a.w, dv1b.x, dv1b.y, dv1b.z, dv1b.w};
        union { unsigned short us[8]; b16x8 v; } pa0, pa1;
        float dp = 0.f;
        for (int e = 0; e < 8; ++e) {
            float x0 = sreg + dv0[e];  x0 = x0 > 0.f ? x0 : 0.2f * x0;
            float x1 = sreg + dv1[e];  x1 = x1 > 0.f ? x1 : 0.2f * x1;
            const float e0 = am0[e] != 0 ? __expf(x0) : 0.f;
            const float e1 = am1[e] != 0 ? __expf(x1) : 0.f;
            dp += e0 + e1;
            pa0.us[e] = f2bf(e0); pa1.us[e] = f2bf(e1);
        }
        denl += dp;
        // MFMA: acc[nt] over head-h columns
        for (int nt = 0; nt < 8; ++nt)
            acc[nt] = __builtin_amdgcn_mfma_f32_16x16x32_bf16(
                pa0.v, bfr[0][nt], acc[nt], 0, 0, 0);
        for (int nt = 0; nt < 8; ++nt)
            acc[nt] = __builtin_amdgcn_mfma_f32_16x16x32_bf16(
                pa1.v, bfr[1][nt], acc[nt], 0, 0, 0);
        aC0 = aP0; aC1 = aP1; aC2 = aP2; aC3 = aP3;
    }
    // den: reduce across quad (lane bits 4,5); lane's partial covers its row l15
    denl += __shfl_xor(denl, 16);
    denl += __shfl_xor(denl, 32);
    if (quad == 0)
        den_part[((size_t)chunk * 2 + h) * NN + irow] = denl;
    // num: acc[nt][r] -> n = i0+grp*16+quad*4+r, c = h*128+nt*16+l15
    float* np_ = num_part + (size_t)chunk * NN * CD;
    const int nrow = i0 + grp * 16 + quad * 4;
    for (int nt = 0; nt < 8; ++nt)
        for (int r = 0; r < 4; ++r)
            np_[(size_t)(nrow + r) * CD + h * 128 + nt * 16 + l15] = acc[nt][r];
}

// ---------------------------------------------------------------------------
// Kernel 3: combine partials, normalize, mean over heads.  grid=4096
// ---------------------------------------------------------------------------
__global__ __launch_bounds__(256) void k_combine(
    const float* __restrict__ num_part, const float* __restrict__ den_part,
    float* __restrict__ out, int jsplit)
{
    const int idx = blockIdx.x * 256 + threadIdx.x;   // NN*FD
    const int n = idx >> 7, f = idx & 127;
    const size_t row = (size_t)n * CD;
    float n0 = 0.f, n1 = 0.f, d0 = 0.f, d1 = 0.f;
    for (int c = 0; c < jsplit; ++c) {
        const size_t base = (size_t)c * NN * CD;
        n0 += num_part[base + row + f];
        n1 += num_part[base + row + 128 + f];
        d0 += den_part[((size_t)c * 2 + 0) * NN + n];
        d1 += den_part[((size_t)c * 2 + 1) * NN + n];
    }
    const float r0 = d0 != 0.f ? n0 / d0 : 0.f;
    const float r1 = d1 != 0.f ? n1 / d1 : 0.f;
    out[idx] = 0.5f * (r0 + r1);
}

// ---------------------------------------------------------------------------
extern "C" void kernel_launch(void* const* d_in, const int* in_sizes, int n_in,
                              void* d_out, int out_size, void* d_ws, size_t ws_size,
                              hipStream_t stream) {
    const float* feat = (const float*)d_in[0];
    const int*   adj  = (const int*)d_in[1];
    const float* W    = (const float*)d_in[2];
    const float* asrc = (const float*)d_in[3];
    const float* adst = (const float*)d_in[4];
    float* out = (float*)d_out;

    // jsplit=4 needs 8MB + 4*8MB = 40MB of ws; fall back to 2 (24MB) if short
    const int jsplit = (ws_size >= ((size_t)40 << 20)) ? 4 : 2;
    const int jchunk = NN / jsplit;

    char* ws = (char*)d_ws;
    unsigned short* Tt = (unsigned short*)ws;                       // 4 MB
    float* s    = (float*)(ws + ((size_t)4 << 20));                 // 64 KB
    float* dsc  = (float*)(ws + ((size_t)4 << 20) + (64 << 10));    // 64 KB
    float* den  = (float*)(ws + ((size_t)4 << 20) + (128 << 10));   // <=256 KB
    float* nump = (float*)(ws + ((size_t)8 << 20));                 // jsplit*8 MB

    k_transform<<<128, 256, 0, stream>>>(feat, W, asrc, adst, Tt, s, dsc);
    k_gat<<<dim3(NN / BI, jsplit), 256, 0, stream>>>(adj, Tt, s, dsc, nump, den, jchunk);
    k_combine<<<NN * FD / 256, 256, 0, stream>>>(nump, den, out, jsplit);
}

// Round 3
// 477.568 us; speedup vs baseline: 1.0874x; 1.0874x over previous
//
#include <hip/hip_runtime.h>
#include <stdint.h>
#include <stddef.h>

#define NN 8192      // nodes
#define KD 256       // in_dim
#define CD 256       // out_dim*heads
#define FD 128       // out_dim
#define BI 64        // i-tile rows per block (k_gat)  [v4: 32 -> 64]
#define BJ 64        // j-tile

typedef __attribute__((ext_vector_type(4))) float f32x4;
typedef __attribute__((ext_vector_type(8))) short b16x8;

__device__ __forceinline__ unsigned short f2bf(float x) {
    unsigned int u = __float_as_uint(x);
    u += 0x7fffu + ((u >> 16) & 1u);
    return (unsigned short)(u >> 16);
}

// async global->LDS, 16B per lane; lds dest = wave-uniform base + lane*16
__device__ __forceinline__ void async16(const void* g, void* l) {
    __builtin_amdgcn_global_load_lds(
        (const __attribute__((address_space(1))) unsigned int*)g,
        (__attribute__((address_space(3))) unsigned int*)l, 16, 0, 0);
}

// ---------------------------------------------------------------------------
// Kernel 1: T = feat @ W.T (bf16 MFMA) fused with:
//   - scores s[n,h], d[n,h] from fp32 accumulators (shfl reduce)
//   - transposed bf16 output Tt[c][n]
// grid=128, block=256   (round-0 version, verbatim)
// ---------------------------------------------------------------------------
__global__ __launch_bounds__(256) void k_transform(
    const float* __restrict__ feat, const float* __restrict__ W,
    const float* __restrict__ asrc, const float* __restrict__ adst,
    unsigned short* __restrict__ Tt, float* __restrict__ s, float* __restrict__ d)
{
    __shared__ unsigned short a_lds[64 * 32];    // 4KB
    __shared__ unsigned short b_lds[256 * 32];   // 16KB
    __shared__ unsigned short tr_lds[256 * 72];  // 36KB
    __shared__ float sc_lds[4][64];              // 1KB
    __shared__ float dc_lds[4][64];              // 1KB

    const int t = threadIdx.x;
    const int wave = t >> 6, lane = t & 63;
    const int l15 = lane & 15, quad = lane >> 4;
    const int n0 = blockIdx.x * 64;
    const int ai = t >> 2, ag = t & 3;

    f32x4 acc[4][4] = {};
    for (int kc = 0; kc < 8; ++kc) {
        const int k0 = kc * 32;
        __syncthreads();
        { // stage A: features[n0+ai][k0 + ag*8 .. +7] -> bf16
            const float* src = feat + (size_t)(n0 + ai) * KD + k0 + ag * 8;
            const float4 v0 = *(const float4*)src;
            const float4 v1 = *(const float4*)(src + 4);
            union { unsigned short us[8]; b16x8 v; } pk;
            pk.us[0] = f2bf(v0.x); pk.us[1] = f2bf(v0.y);
            pk.us[2] = f2bf(v0.z); pk.us[3] = f2bf(v0.w);
            pk.us[4] = f2bf(v1.x); pk.us[5] = f2bf(v1.y);
            pk.us[6] = f2bf(v1.z); pk.us[7] = f2bf(v1.w);
            const int slot = ag ^ ((ai >> 1) & 3);
            *(b16x8*)&a_lds[ai * 32 + slot * 8] = pk.v;
        }
        for (int p = 0; p < 4; ++p) { // stage B: W[c][k0 + g*8 .. +7]
            const int G = p * 256 + t;
            const int c = G >> 2, g = G & 3;
            const float* src = W + (size_t)c * KD + k0 + g * 8;
            const float4 v0 = *(const float4*)src;
            const float4 v1 = *(const float4*)(src + 4);
            union { unsigned short us[8]; b16x8 v; } pk;
            pk.us[0] = f2bf(v0.x); pk.us[1] = f2bf(v0.y);
            pk.us[2] = f2bf(v0.z); pk.us[3] = f2bf(v0.w);
            pk.us[4] = f2bf(v1.x); pk.us[5] = f2bf(v1.y);
            pk.us[6] = f2bf(v1.z); pk.us[7] = f2bf(v1.w);
            const int slot = g ^ ((c >> 1) & 3);
            *(b16x8*)&b_lds[c * 32 + slot * 8] = pk.v;
        }
        __syncthreads();
        b16x8 af[4], bfr[4];
        for (int mt = 0; mt < 4; ++mt) {
            const int m = mt * 16 + l15;
            af[mt] = *(const b16x8*)&a_lds[m * 32 + (quad ^ ((m >> 1) & 3)) * 8];
        }
        for (int nt = 0; nt < 4; ++nt) {
            const int c = wave * 64 + nt * 16 + l15;
            bfr[nt] = *(const b16x8*)&b_lds[c * 32 + (quad ^ ((c >> 1) & 3)) * 8];
        }
        for (int mt = 0; mt < 4; ++mt)
            for (int nt = 0; nt < 4; ++nt)
                acc[mt][nt] = __builtin_amdgcn_mfma_f32_16x16x32_bf16(
                    af[mt], bfr[nt], acc[mt][nt], 0, 0, 0);
    }

    // ---- epilogue: scores (fp32) + transposed bf16 store ----
    float aS[4], aD[4];
    for (int nt = 0; nt < 4; ++nt) {
        const int c = wave * 64 + nt * 16 + l15;
        aS[nt] = asrc[c]; aD[nt] = adst[c];
    }
    for (int mt = 0; mt < 4; ++mt)
        for (int r = 0; r < 4; ++r) {
            float vs = 0.f, vd = 0.f;
            for (int nt = 0; nt < 4; ++nt) {
                const float x = acc[mt][nt][r];
                vs += x * aS[nt]; vd += x * aD[nt];
            }
            vs += __shfl_xor(vs, 1); vd += __shfl_xor(vd, 1);
            vs += __shfl_xor(vs, 2); vd += __shfl_xor(vd, 2);
            vs += __shfl_xor(vs, 4); vd += __shfl_xor(vd, 4);
            vs += __shfl_xor(vs, 8); vd += __shfl_xor(vd, 8);
            if (l15 == 0) {
                const int nl = mt * 16 + quad * 4 + r;
                sc_lds[wave][nl] = vs; dc_lds[wave][nl] = vd;
            }
        }
    for (int mt = 0; mt < 4; ++mt)
        for (int nt = 0; nt < 4; ++nt)
            for (int r = 0; r < 4; ++r) {
                const int c = wave * 64 + nt * 16 + l15;
                const int n = mt * 16 + quad * 4 + r;
                tr_lds[c * 72 + n] = f2bf(acc[mt][nt][r]);
            }
    __syncthreads();
    if (t < 128) {
        const int n = t >> 1, h = t & 1;
        s[(size_t)(n0 + n) * 2 + h] = sc_lds[h * 2][n] + sc_lds[h * 2 + 1][n];
        d[(size_t)(n0 + n) * 2 + h] = dc_lds[h * 2][n] + dc_lds[h * 2 + 1][n];
    }
    for (int p = 0; p < 8; ++p) {
        const int idx = p * 256 + t;       // 2048 granules
        const int c = idx >> 3, g = idx & 7;
        *(b16x8*)(Tt + (size_t)c * NN + n0 + g * 8) = *(const b16x8*)&tr_lds[c * 72 + g * 8];
    }
}

// ---------------------------------------------------------------------------
// Kernel 2 (v4): round-0 structure scaled to BI=64 / 512 threads / 8 waves.
//   The 32KB Tt stage now serves 2x the output rows -> per-CU L1 bytes per
//   unit work drop ~1.7x (this was the bottleneck; sync-structure changes in
//   v2/v3 both regressed).  Wave role: (h, fh, rh) each computing 32x64.
//   Adjacency (the HBM stream) register-prefetched one j-tile ahead, issued
//   right after the first barrier so its latency hides under the exp phase.
//   LDS 48KB -> grid-limited 2 blocks/CU, 16 waves/CU.
// ---------------------------------------------------------------------------
__global__ __launch_bounds__(512, 4) void k_gat(
    const int* __restrict__ adj, const unsigned short* __restrict__ Tt,
    const float* __restrict__ s, const float* __restrict__ d,
    float* __restrict__ num_part,   // [jsplit][NN][CD]
    float* __restrict__ den_part,   // [jsplit][2][NN]
    int jchunk)
{
    __shared__ unsigned short tt_lds[CD * BJ];       // 32KB (global-addr permuted)
    __shared__ unsigned short w_lds[2 * BI * BJ];    // 16KB, XOR-swizzled

    const int t = threadIdx.x;
    const int w = t >> 6, lane = t & 63;
    const int l15 = lane & 15, quad = lane >> 4;
    const int h  = (w >> 2) & 1;    // head
    const int fh = (w >> 1) & 1;    // f-half
    const int rh = w & 1;           // row-half
    const int i0 = blockIdx.x * BI;
    const int chunk = blockIdx.y;
    const int jbase = chunk * jchunk;

    const int wi = t >> 3;          // 0..63 : row within i-tile
    const int j8 = t & 7;           // 0..7  : 8-wide j granule
    const int gi = i0 + wi;
    const float s0 = s[(size_t)gi * 2 + 0];
    const float s1 = s[(size_t)gi * 2 + 1];
    const int cbase = h * 128 + fh * 64;

    f32x4 acc[2][4] = {};
    float den0 = 0.f, den1 = 0.f;
    const int njt = jchunk / BJ;

    // prefetch iter-0 adjacency (the only HBM-latency stream)
    const int* arow = adj + (size_t)gi * NN + j8 * 8;
    int4 a0p = *(const int4*)(arow + jbase);
    int4 a1p = *(const int4*)(arow + jbase + 4);

    for (int jt = 0; jt < njt; ++jt) {
        const int j0 = jbase + jt * BJ;
        __syncthreads();   // prior MFMA reads of tt_lds/w_lds done
        // d scores early (L2-hot; latency overlaps staging issue + exp)
        const float4* dvp = (const float4*)(d + (size_t)(j0 + j8 * 8) * 2);
        union { float4 v[4]; float f[16]; } dv;
        dv.v[0] = dvp[0]; dv.v[1] = dvp[1]; dv.v[2] = dvp[2]; dv.v[3] = dvp[3];
        // async Tt tile stage (global-addr permuted to keep XOR swizzle)
        for (int p = 0; p < 4; ++p) {
            const int G = (p * 8 + w) * 64 + lane;      // 2048 linear granules
            const int c = G >> 3, gt = G & 7;
            const int g = gt ^ (c & 7);                 // inverse perm on global side
            async16(Tt + (size_t)c * NN + j0 + g * 8,
                    (char*)tt_lds + (size_t)(p * 8 + w) * 1024);
        }
        // prefetch NEXT tile's adjacency (in flight through exp + w-write)
        const int jn = (jt + 1 < njt) ? j0 + BJ : jbase;
        const int4 aN0 = *(const int4*)(arow + jn);
        const int4 aN1 = *(const int4*)(arow + jn + 4);
        // masked exp(leaky) weights from PREFETCHED adjacency regs
        const int am[8] = {a0p.x, a0p.y, a0p.z, a0p.w, a1p.x, a1p.y, a1p.z, a1p.w};
        union { unsigned short us[8]; b16x8 v; } w0, w1;
        float dp0 = 0.f, dp1 = 0.f;
        for (int e = 0; e < 8; ++e) {
            float x0 = s0 + dv.f[e * 2 + 0];  x0 = x0 > 0.f ? x0 : 0.2f * x0;
            float x1 = s1 + dv.f[e * 2 + 1];  x1 = x1 > 0.f ? x1 : 0.2f * x1;
            const float e0 = am[e] != 0 ? __expf(x0) : 0.f;
            const float e1 = am[e] != 0 ? __expf(x1) : 0.f;
            dp0 += e0; dp1 += e1;
            w0.us[e] = f2bf(e0); w1.us[e] = f2bf(e1);
        }
        den0 += dp0; den1 += dp1;
        const int slot = (j8 ^ (wi & 7)) << 3;
        *(b16x8*)&w_lds[(0 * BI + wi) * BJ + slot] = w0.v;
        *(b16x8*)&w_lds[(1 * BI + wi) * BJ + slot] = w1.v;
        a0p = aN0; a1p = aN1;
        __syncthreads();   // w_lds ready; drains async tt loads
        // --- MFMA: num[i0+rh*32.., cbase..cbase+63] += w_h @ T ---
        for (int ks = 0; ks < 2; ++ks) {
            const int gidx = ks * 4 + quad;
            b16x8 af[2], bfr[4];
            for (int mt = 0; mt < 2; ++mt) {
                const int m = rh * 32 + mt * 16 + l15;
                af[mt] = *(const b16x8*)&w_lds[(h * BI + m) * BJ + ((gidx ^ (m & 7)) << 3)];
            }
            for (int nt = 0; nt < 4; ++nt) {
                const int c = cbase + nt * 16 + l15;
                bfr[nt] = *(const b16x8*)&tt_lds[c * BJ + ((gidx ^ (c & 7)) << 3)];
            }
            for (int mt = 0; mt < 2; ++mt)
                for (int nt = 0; nt < 4; ++nt)
                    acc[mt][nt] = __builtin_amdgcn_mfma_f32_16x16x32_bf16(
                        af[mt], bfr[nt], acc[mt][nt], 0, 0, 0);
        }
    }
    // reduce den over the 8 j8-lanes (lane bits 0..2)
    den0 += __shfl_xor(den0, 1); den0 += __shfl_xor(den0, 2); den0 += __shfl_xor(den0, 4);
    den1 += __shfl_xor(den1, 1); den1 += __shfl_xor(den1, 2); den1 += __shfl_xor(den1, 4);
    if (j8 == 0) {
        den_part[((size_t)chunk * 2 + 0) * NN + gi] = den0;
        den_part[((size_t)chunk * 2 + 1) * NN + gi] = den1;
    }
    float* np_ = num_part + (size_t)chunk * NN * CD;
    for (int mt = 0; mt < 2; ++mt)
        for (int nt = 0; nt < 4; ++nt)
            for (int r = 0; r < 4; ++r) {
                const int n = i0 + rh * 32 + mt * 16 + quad * 4 + r;
                const int c = cbase + nt * 16 + l15;
                np_[(size_t)n * CD + c] = acc[mt][nt][r];
            }
}

// ---------------------------------------------------------------------------
// Kernel 3: combine partials, normalize, mean over heads.  grid=4096
// ---------------------------------------------------------------------------
__global__ __launch_bounds__(256) void k_combine(
    const float* __restrict__ num_part, const float* __restrict__ den_part,
    float* __restrict__ out, int jsplit)
{
    const int idx = blockIdx.x * 256 + threadIdx.x;   // NN*FD
    const int n = idx >> 7, f = idx & 127;
    const size_t row = (size_t)n * CD;
    float n0 = 0.f, n1 = 0.f, d0 = 0.f, d1 = 0.f;
    for (int c = 0; c < jsplit; ++c) {
        const size_t base = (size_t)c * NN * CD;
        n0 += num_part[base + row + f];
        n1 += num_part[base + row + 128 + f];
        d0 += den_part[((size_t)c * 2 + 0) * NN + n];
        d1 += den_part[((size_t)c * 2 + 1) * NN + n];
    }
    const float r0 = d0 != 0.f ? n0 / d0 : 0.f;
    const float r1 = d1 != 0.f ? n1 / d1 : 0.f;
    out[idx] = 0.5f * (r0 + r1);
}

// ---------------------------------------------------------------------------
extern "C" void kernel_launch(void* const* d_in, const int* in_sizes, int n_in,
                              void* d_out, int out_size, void* d_ws, size_t ws_size,
                              hipStream_t stream) {
    const float* feat = (const float*)d_in[0];
    const int*   adj  = (const int*)d_in[1];
    const float* W    = (const float*)d_in[2];
    const float* asrc = (const float*)d_in[3];
    const float* adst = (const float*)d_in[4];
    float* out = (float*)d_out;

    // jsplit=8 needs 8+64MB; jsplit=4 needs 8+32MB; else 2
    const int jsplit = (ws_size >= ((size_t)73 << 20)) ? 8
                     : (ws_size >= ((size_t)40 << 20)) ? 4 : 2;
    const int jchunk = NN / jsplit;

    char* ws = (char*)d_ws;
    unsigned short* Tt = (unsigned short*)ws;                       // 4 MB
    float* s    = (float*)(ws + ((size_t)4 << 20));                 // 64 KB
    float* dsc  = (float*)(ws + ((size_t)4 << 20) + (64 << 10));    // 64 KB
    float* den  = (float*)(ws + ((size_t)4 << 20) + (128 << 10));   // <=512 KB
    float* nump = (float*)(ws + ((size_t)8 << 20));                 // jsplit*8 MB

    k_transform<<<128, 256, 0, stream>>>(feat, W, asrc, adst, Tt, s, dsc);
    k_gat<<<dim3(NN / BI, jsplit), 512, 0, stream>>>(adj, Tt, s, dsc, nump, den, jchunk);
    k_combine<<<NN * FD / 256, 256, 0, stream>>>(nump, den, out, jsplit);
}

// Round 4
// 448.696 us; speedup vs baseline: 1.1574x; 1.0643x over previous
//
#include <hip/hip_runtime.h>
#include <stdint.h>
#include <stddef.h>

#define NN 8192      // nodes
#define KD 256       // in_dim
#define CD 256       // out_dim*heads
#define FD 128       // out_dim
#define BI 64        // i-tile rows per block (k_gat)
#define BJ 64        // j-tile

typedef __attribute__((ext_vector_type(4))) float f32x4;
typedef __attribute__((ext_vector_type(8))) short b16x8;

__device__ __forceinline__ unsigned short f2bf(float x) {
    unsigned int u = __float_as_uint(x);
    u += 0x7fffu + ((u >> 16) & 1u);
    return (unsigned short)(u >> 16);
}

// async global->LDS, 16B per lane; lds dest = wave-uniform base + lane*16
__device__ __forceinline__ void async16(const void* g, void* l) {
    __builtin_amdgcn_global_load_lds(
        (const __attribute__((address_space(1))) unsigned int*)g,
        (__attribute__((address_space(3))) unsigned int*)l, 16, 0, 0);
}

// ---------------------------------------------------------------------------
// Kernel 1: T = feat @ W.T (bf16 MFMA) fused with scores; round-0 verbatim.
// grid=128, block=256
// ---------------------------------------------------------------------------
__global__ __launch_bounds__(256) void k_transform(
    const float* __restrict__ feat, const float* __restrict__ W,
    const float* __restrict__ asrc, const float* __restrict__ adst,
    unsigned short* __restrict__ Tt, float* __restrict__ s, float* __restrict__ d)
{
    __shared__ unsigned short a_lds[64 * 32];    // 4KB
    __shared__ unsigned short b_lds[256 * 32];   // 16KB
    __shared__ unsigned short tr_lds[256 * 72];  // 36KB
    __shared__ float sc_lds[4][64];              // 1KB
    __shared__ float dc_lds[4][64];              // 1KB

    const int t = threadIdx.x;
    const int wave = t >> 6, lane = t & 63;
    const int l15 = lane & 15, quad = lane >> 4;
    const int n0 = blockIdx.x * 64;
    const int ai = t >> 2, ag = t & 3;

    f32x4 acc[4][4] = {};
    for (int kc = 0; kc < 8; ++kc) {
        const int k0 = kc * 32;
        __syncthreads();
        { // stage A: features[n0+ai][k0 + ag*8 .. +7] -> bf16
            const float* src = feat + (size_t)(n0 + ai) * KD + k0 + ag * 8;
            const float4 v0 = *(const float4*)src;
            const float4 v1 = *(const float4*)(src + 4);
            union { unsigned short us[8]; b16x8 v; } pk;
            pk.us[0] = f2bf(v0.x); pk.us[1] = f2bf(v0.y);
            pk.us[2] = f2bf(v0.z); pk.us[3] = f2bf(v0.w);
            pk.us[4] = f2bf(v1.x); pk.us[5] = f2bf(v1.y);
            pk.us[6] = f2bf(v1.z); pk.us[7] = f2bf(v1.w);
            const int slot = ag ^ ((ai >> 1) & 3);
            *(b16x8*)&a_lds[ai * 32 + slot * 8] = pk.v;
        }
        for (int p = 0; p < 4; ++p) { // stage B: W[c][k0 + g*8 .. +7]
            const int G = p * 256 + t;
            const int c = G >> 2, g = G & 3;
            const float* src = W + (size_t)c * KD + k0 + g * 8;
            const float4 v0 = *(const float4*)src;
            const float4 v1 = *(const float4*)(src + 4);
            union { unsigned short us[8]; b16x8 v; } pk;
            pk.us[0] = f2bf(v0.x); pk.us[1] = f2bf(v0.y);
            pk.us[2] = f2bf(v0.z); pk.us[3] = f2bf(v0.w);
            pk.us[4] = f2bf(v1.x); pk.us[5] = f2bf(v1.y);
            pk.us[6] = f2bf(v1.z); pk.us[7] = f2bf(v1.w);
            const int slot = g ^ ((c >> 1) & 3);
            *(b16x8*)&b_lds[c * 32 + slot * 8] = pk.v;
        }
        __syncthreads();
        b16x8 af[4], bfr[4];
        for (int mt = 0; mt < 4; ++mt) {
            const int m = mt * 16 + l15;
            af[mt] = *(const b16x8*)&a_lds[m * 32 + (quad ^ ((m >> 1) & 3)) * 8];
        }
        for (int nt = 0; nt < 4; ++nt) {
            const int c = wave * 64 + nt * 16 + l15;
            bfr[nt] = *(const b16x8*)&b_lds[c * 32 + (quad ^ ((c >> 1) & 3)) * 8];
        }
        for (int mt = 0; mt < 4; ++mt)
            for (int nt = 0; nt < 4; ++nt)
                acc[mt][nt] = __builtin_amdgcn_mfma_f32_16x16x32_bf16(
                    af[mt], bfr[nt], acc[mt][nt], 0, 0, 0);
    }

    // ---- epilogue: scores (fp32) + transposed bf16 store ----
    float aS[4], aD[4];
    for (int nt = 0; nt < 4; ++nt) {
        const int c = wave * 64 + nt * 16 + l15;
        aS[nt] = asrc[c]; aD[nt] = adst[c];
    }
    for (int mt = 0; mt < 4; ++mt)
        for (int r = 0; r < 4; ++r) {
            float vs = 0.f, vd = 0.f;
            for (int nt = 0; nt < 4; ++nt) {
                const float x = acc[mt][nt][r];
                vs += x * aS[nt]; vd += x * aD[nt];
            }
            vs += __shfl_xor(vs, 1); vd += __shfl_xor(vd, 1);
            vs += __shfl_xor(vs, 2); vd += __shfl_xor(vd, 2);
            vs += __shfl_xor(vs, 4); vd += __shfl_xor(vd, 4);
            vs += __shfl_xor(vs, 8); vd += __shfl_xor(vd, 8);
            if (l15 == 0) {
                const int nl = mt * 16 + quad * 4 + r;
                sc_lds[wave][nl] = vs; dc_lds[wave][nl] = vd;
            }
        }
    for (int mt = 0; mt < 4; ++mt)
        for (int nt = 0; nt < 4; ++nt)
            for (int r = 0; r < 4; ++r) {
                const int c = wave * 64 + nt * 16 + l15;
                const int n = mt * 16 + quad * 4 + r;
                tr_lds[c * 72 + n] = f2bf(acc[mt][nt][r]);
            }
    __syncthreads();
    if (t < 128) {
        const int n = t >> 1, h = t & 1;
        s[(size_t)(n0 + n) * 2 + h] = sc_lds[h * 2][n] + sc_lds[h * 2 + 1][n];
        d[(size_t)(n0 + n) * 2 + h] = dc_lds[h * 2][n] + dc_lds[h * 2 + 1][n];
    }
    for (int p = 0; p < 8; ++p) {
        const int idx = p * 256 + t;       // 2048 granules
        const int c = idx >> 3, g = idx & 7;
        *(b16x8*)(Tt + (size_t)c * NN + n0 + g * 8) = *(const b16x8*)&tr_lds[c * 72 + g * 8];
    }
}

// ---------------------------------------------------------------------------
// Kernel 2 (v5): v4 skeleton + software pipeline.
//   tt_lds double-buffered; DMA for tile jt+1 issued right after the loop-top
//   raw s_barrier (into the buffer MFMA(jt-1) just released); adj + d both
//   register-prefetched one tile ahead.  Pre-MFMA barrier uses a COUNTED
//   s_waitcnt vmcnt(10) (= this iter's 4 DMA + 2 adj + 4 d still in flight),
//   never vmcnt(0): tile jt+1's loads stay outstanding across the barrier and
//   the MFMA phase.  LDS 80KB -> exactly 2 blocks/CU, grid 512 = zero tail.
// ---------------------------------------------------------------------------
__global__ __launch_bounds__(512, 4) void k_gat(
    const int* __restrict__ adj, const unsigned short* __restrict__ Tt,
    const float* __restrict__ s, const float* __restrict__ d,
    float* __restrict__ num_part,   // [jsplit][NN][CD]
    float* __restrict__ den_part,   // [jsplit][2][NN]
    int jchunk)
{
    __shared__ unsigned short tt_lds[2][CD * BJ];    // 2 x 32KB
    __shared__ unsigned short w_lds[2 * BI * BJ];    // 16KB, XOR-swizzled

    const int t = threadIdx.x;
    const int w = t >> 6, lane = t & 63;
    const int l15 = lane & 15, quad = lane >> 4;
    const int h  = (w >> 2) & 1;    // head
    const int fh = (w >> 1) & 1;    // f-half
    const int rh = w & 1;           // row-half
    const int i0 = blockIdx.x * BI;
    const int chunk = blockIdx.y;
    const int jbase = chunk * jchunk;

    const int wi = t >> 3;          // 0..63 : row within i-tile
    const int j8 = t & 7;           // 0..7  : 8-wide j granule
    const int gi = i0 + wi;
    const float s0 = s[(size_t)gi * 2 + 0];
    const float s1 = s[(size_t)gi * 2 + 1];
    const int cbase = h * 128 + fh * 64;

    f32x4 acc[2][4] = {};
    float den0 = 0.f, den1 = 0.f;
    const int njt = jchunk / BJ;

    const int* arow = adj + (size_t)gi * NN + j8 * 8;

    // ---- prologue: stage tile 0 -> buf 0; prefetch adj+d for tile 0 ----
    for (int p = 0; p < 4; ++p) {
        const int G = (p * 8 + w) * 64 + lane;
        const int c = G >> 3, gt = G & 7;
        const int g = gt ^ (c & 7);
        async16(Tt + (size_t)c * NN + jbase + g * 8,
                (char*)&tt_lds[0][0] + (size_t)(p * 8 + w) * 1024);
    }
    int4 aC0 = *(const int4*)(arow + jbase);
    int4 aC1 = *(const int4*)(arow + jbase + 4);
    const float4* dcp = (const float4*)(d + (size_t)(jbase + j8 * 8) * 2);
    float4 dC0 = dcp[0], dC1 = dcp[1], dC2 = dcp[2], dC3 = dcp[3];

    for (int jt = 0; jt < njt; ++jt) {
        const int j0 = jbase + jt * BJ;
        const int cur = jt & 1;
        // all waves finished MFMA(jt-1) -> its tt buffer + w_lds are free
        __builtin_amdgcn_s_barrier();
        // stage NEXT tile into the released buffer (latency hides under exp+MFMA)
        const int jn = (jt + 1 < njt) ? j0 + BJ : j0;
        for (int p = 0; p < 4; ++p) {
            const int G = (p * 8 + w) * 64 + lane;
            const int c = G >> 3, gt = G & 7;
            const int g = gt ^ (c & 7);
            async16(Tt + (size_t)c * NN + jn + g * 8,
                    (char*)&tt_lds[cur ^ 1][0] + (size_t)(p * 8 + w) * 1024);
        }
        // prefetch next adj + d as registers (issued AFTER the DMAs so the
        // compiler's wait for the CURRENT regs never drains the DMA queue)
        const int4 aN0 = *(const int4*)(arow + jn);
        const int4 aN1 = *(const int4*)(arow + jn + 4);
        const float4* dnp = (const float4*)(d + (size_t)(jn + j8 * 8) * 2);
        const float4 dN0 = dnp[0], dN1 = dnp[1], dN2 = dnp[2], dN3 = dnp[3];
        // exp weights for CURRENT tile, all inputs already in registers
        const int am[8] = {aC0.x, aC0.y, aC0.z, aC0.w, aC1.x, aC1.y, aC1.z, aC1.w};
        union { float4 v[4]; float f[16]; } dv;
        dv.v[0] = dC0; dv.v[1] = dC1; dv.v[2] = dC2; dv.v[3] = dC3;
        union { unsigned short us[8]; b16x8 v; } w0, w1;
        float dp0 = 0.f, dp1 = 0.f;
        for (int e = 0; e < 8; ++e) {
            float x0 = s0 + dv.f[e * 2 + 0];  x0 = x0 > 0.f ? x0 : 0.2f * x0;
            float x1 = s1 + dv.f[e * 2 + 1];  x1 = x1 > 0.f ? x1 : 0.2f * x1;
            const float e0 = am[e] != 0 ? __expf(x0) : 0.f;
            const float e1 = am[e] != 0 ? __expf(x1) : 0.f;
            dp0 += e0; dp1 += e1;
            w0.us[e] = f2bf(e0); w1.us[e] = f2bf(e1);
        }
        den0 += dp0; den1 += dp1;
        const int slot = (j8 ^ (wi & 7)) << 3;
        *(b16x8*)&w_lds[(0 * BI + wi) * BJ + slot] = w0.v;
        *(b16x8*)&w_lds[(1 * BI + wi) * BJ + slot] = w1.v;
        aC0 = aN0; aC1 = aN1; dC0 = dN0; dC1 = dN1; dC2 = dN2; dC3 = dN3;
        // COUNTED wait: exactly 10 VMEM (4 DMA + 2 adj + 4 d, all for jt+1)
        // were issued this iter -> vmcnt(10) guarantees tile jt's DMAs landed
        // while jt+1's stay in flight.  lgkmcnt(0): w_lds writes visible.
        asm volatile("s_waitcnt vmcnt(10) lgkmcnt(0)" ::: "memory");
        __builtin_amdgcn_s_barrier();
        __builtin_amdgcn_sched_barrier(0);
        // --- MFMA: num[i0+rh*32.., cbase..cbase+63] += w_h @ T ---
        for (int ks = 0; ks < 2; ++ks) {
            const int gidx = ks * 4 + quad;
            b16x8 af[2], bfr[4];
            for (int mt = 0; mt < 2; ++mt) {
                const int m = rh * 32 + mt * 16 + l15;
                af[mt] = *(const b16x8*)&w_lds[(h * BI + m) * BJ + ((gidx ^ (m & 7)) << 3)];
            }
            for (int nt = 0; nt < 4; ++nt) {
                const int c = cbase + nt * 16 + l15;
                bfr[nt] = *(const b16x8*)&tt_lds[cur][c * BJ + ((gidx ^ (c & 7)) << 3)];
            }
            for (int mt = 0; mt < 2; ++mt)
                for (int nt = 0; nt < 4; ++nt)
                    acc[mt][nt] = __builtin_amdgcn_mfma_f32_16x16x32_bf16(
                        af[mt], bfr[nt], acc[mt][nt], 0, 0, 0);
        }
    }
    // drain tail DMAs before the wave can retire / LDS be reallocated
    asm volatile("s_waitcnt vmcnt(0)" ::: "memory");
    // reduce den over the 8 j8-lanes (lane bits 0..2)
    den0 += __shfl_xor(den0, 1); den0 += __shfl_xor(den0, 2); den0 += __shfl_xor(den0, 4);
    den1 += __shfl_xor(den1, 1); den1 += __shfl_xor(den1, 2); den1 += __shfl_xor(den1, 4);
    if (j8 == 0) {
        den_part[((size_t)chunk * 2 + 0) * NN + gi] = den0;
        den_part[((size_t)chunk * 2 + 1) * NN + gi] = den1;
    }
    float* np_ = num_part + (size_t)chunk * NN * CD;
    for (int mt = 0; mt < 2; ++mt)
        for (int nt = 0; nt < 4; ++nt)
            for (int r = 0; r < 4; ++r) {
                const int n = i0 + rh * 32 + mt * 16 + quad * 4 + r;
                const int c = cbase + nt * 16 + l15;
                np_[(size_t)n * CD + c] = acc[mt][nt][r];
            }
}

// ---------------------------------------------------------------------------
// Kernel 3: combine partials, normalize, mean over heads.  grid=4096
// ---------------------------------------------------------------------------
__global__ __launch_bounds__(256) void k_combine(
    const float* __restrict__ num_part, const float* __restrict__ den_part,
    float* __restrict__ out, int jsplit)
{
    const int idx = blockIdx.x * 256 + threadIdx.x;   // NN*FD
    const int n = idx >> 7, f = idx & 127;
    const size_t row = (size_t)n * CD;
    float n0 = 0.f, n1 = 0.f, d0 = 0.f, d1 = 0.f;
    for (int c = 0; c < jsplit; ++c) {
        const size_t base = (size_t)c * NN * CD;
        n0 += num_part[base + row + f];
        n1 += num_part[base + row + 128 + f];
        d0 += den_part[((size_t)c * 2 + 0) * NN + n];
        d1 += den_part[((size_t)c * 2 + 1) * NN + n];
    }
    const float r0 = d0 != 0.f ? n0 / d0 : 0.f;
    const float r1 = d1 != 0.f ? n1 / d1 : 0.f;
    out[idx] = 0.5f * (r0 + r1);
}

// ---------------------------------------------------------------------------
extern "C" void kernel_launch(void* const* d_in, const int* in_sizes, int n_in,
                              void* d_out, int out_size, void* d_ws, size_t ws_size,
                              hipStream_t stream) {
    const float* feat = (const float*)d_in[0];
    const int*   adj  = (const int*)d_in[1];
    const float* W    = (const float*)d_in[2];
    const float* asrc = (const float*)d_in[3];
    const float* adst = (const float*)d_in[4];
    float* out = (float*)d_out;

    // jsplit=4 (40MB ws) is the sweet spot: grid 512 = exactly 2 blocks/CU,
    // partial traffic 32MB (jsplit=8 doubled it for no k_gat gain in R3).
    const int jsplit = (ws_size >= ((size_t)40 << 20)) ? 4 : 2;
    const int jchunk = NN / jsplit;

    char* ws = (char*)d_ws;
    unsigned short* Tt = (unsigned short*)ws;                       // 4 MB
    float* s    = (float*)(ws + ((size_t)4 << 20));                 // 64 KB
    float* dsc  = (float*)(ws + ((size_t)4 << 20) + (64 << 10));    // 64 KB
    float* den  = (float*)(ws + ((size_t)4 << 20) + (128 << 10));   // <=256 KB
    float* nump = (float*)(ws + ((size_t)8 << 20));                 // jsplit*8 MB

    k_transform<<<128, 256, 0, stream>>>(feat, W, asrc, adst, Tt, s, dsc);
    k_gat<<<dim3(NN / BI, jsplit), 512, 0, stream>>>(adj, Tt, s, dsc, nump, den, jchunk);
    k_combine<<<NN * FD / 256, 256, 0, stream>>>(nump, den, out, jsplit);
}

// Round 5
// 438.271 us; speedup vs baseline: 1.1849x; 1.0238x over previous
//
#include <hip/hip_runtime.h>
#include <stdint.h>
#include <stddef.h>

#define NN 8192      // nodes
#define KD 256       // in_dim
#define CD 256       // out_dim*heads
#define FD 128       // out_dim
#define BI 64        // i-tile rows per block (k_gat)
#define BJ 64        // j-tile

typedef __attribute__((ext_vector_type(4))) float f32x4;
typedef __attribute__((ext_vector_type(8))) short b16x8;

__device__ __forceinline__ unsigned short f2bf(float x) {
    unsigned int u = __float_as_uint(x);
    u += 0x7fffu + ((u >> 16) & 1u);
    return (unsigned short)(u >> 16);
}

// pack two f32 -> two bf16 (RNE, identical to f2bf) in ONE instruction
__device__ __forceinline__ unsigned int cvtpk(float lo, float hi) {
    unsigned int r;
    asm("v_cvt_pk_bf16_f32 %0, %1, %2" : "=v"(r) : "v"(lo), "v"(hi));
    return r;
}

// async global->LDS, 16B per lane; lds dest = wave-uniform base + lane*16
__device__ __forceinline__ void async16(const void* g, void* l) {
    __builtin_amdgcn_global_load_lds(
        (const __attribute__((address_space(1))) unsigned int*)g,
        (__attribute__((address_space(3))) unsigned int*)l, 16, 0, 0);
}

// ---------------------------------------------------------------------------
// Kernel 1: T = feat @ W.T (bf16 MFMA) fused with scores.
// grid=128, block=256  (round-0 structure; packs via cvt_pk)
// ---------------------------------------------------------------------------
__global__ __launch_bounds__(256) void k_transform(
    const float* __restrict__ feat, const float* __restrict__ W,
    const float* __restrict__ asrc, const float* __restrict__ adst,
    unsigned short* __restrict__ Tt, float* __restrict__ s, float* __restrict__ d)
{
    __shared__ unsigned short a_lds[64 * 32];    // 4KB
    __shared__ unsigned short b_lds[256 * 32];   // 16KB
    __shared__ unsigned short tr_lds[256 * 72];  // 36KB
    __shared__ float sc_lds[4][64];              // 1KB
    __shared__ float dc_lds[4][64];              // 1KB

    const int t = threadIdx.x;
    const int wave = t >> 6, lane = t & 63;
    const int l15 = lane & 15, quad = lane >> 4;
    const int n0 = blockIdx.x * 64;
    const int ai = t >> 2, ag = t & 3;

    f32x4 acc[4][4] = {};
    for (int kc = 0; kc < 8; ++kc) {
        const int k0 = kc * 32;
        __syncthreads();
        { // stage A: features[n0+ai][k0 + ag*8 .. +7] -> bf16
            const float* src = feat + (size_t)(n0 + ai) * KD + k0 + ag * 8;
            const float4 v0 = *(const float4*)src;
            const float4 v1 = *(const float4*)(src + 4);
            union { unsigned int u[4]; b16x8 v; } pk;
            pk.u[0] = cvtpk(v0.x, v0.y); pk.u[1] = cvtpk(v0.z, v0.w);
            pk.u[2] = cvtpk(v1.x, v1.y); pk.u[3] = cvtpk(v1.z, v1.w);
            const int slot = ag ^ ((ai >> 1) & 3);
            *(b16x8*)&a_lds[ai * 32 + slot * 8] = pk.v;
        }
        for (int p = 0; p < 4; ++p) { // stage B: W[c][k0 + g*8 .. +7]
            const int G = p * 256 + t;
            const int c = G >> 2, g = G & 3;
            const float* src = W + (size_t)c * KD + k0 + g * 8;
            const float4 v0 = *(const float4*)src;
            const float4 v1 = *(const float4*)(src + 4);
            union { unsigned int u[4]; b16x8 v; } pk;
            pk.u[0] = cvtpk(v0.x, v0.y); pk.u[1] = cvtpk(v0.z, v0.w);
            pk.u[2] = cvtpk(v1.x, v1.y); pk.u[3] = cvtpk(v1.z, v1.w);
            const int slot = g ^ ((c >> 1) & 3);
            *(b16x8*)&b_lds[c * 32 + slot * 8] = pk.v;
        }
        __syncthreads();
        b16x8 af[4], bfr[4];
        for (int mt = 0; mt < 4; ++mt) {
            const int m = mt * 16 + l15;
            af[mt] = *(const b16x8*)&a_lds[m * 32 + (quad ^ ((m >> 1) & 3)) * 8];
        }
        for (int nt = 0; nt < 4; ++nt) {
            const int c = wave * 64 + nt * 16 + l15;
            bfr[nt] = *(const b16x8*)&b_lds[c * 32 + (quad ^ ((c >> 1) & 3)) * 8];
        }
        for (int mt = 0; mt < 4; ++mt)
            for (int nt = 0; nt < 4; ++nt)
                acc[mt][nt] = __builtin_amdgcn_mfma_f32_16x16x32_bf16(
                    af[mt], bfr[nt], acc[mt][nt], 0, 0, 0);
    }

    // ---- epilogue: scores (fp32) + transposed bf16 store ----
    float aS[4], aD[4];
    for (int nt = 0; nt < 4; ++nt) {
        const int c = wave * 64 + nt * 16 + l15;
        aS[nt] = asrc[c]; aD[nt] = adst[c];
    }
    for (int mt = 0; mt < 4; ++mt)
        for (int r = 0; r < 4; ++r) {
            float vs = 0.f, vd = 0.f;
            for (int nt = 0; nt < 4; ++nt) {
                const float x = acc[mt][nt][r];
                vs += x * aS[nt]; vd += x * aD[nt];
            }
            vs += __shfl_xor(vs, 1); vd += __shfl_xor(vd, 1);
            vs += __shfl_xor(vs, 2); vd += __shfl_xor(vd, 2);
            vs += __shfl_xor(vs, 4); vd += __shfl_xor(vd, 4);
            vs += __shfl_xor(vs, 8); vd += __shfl_xor(vd, 8);
            if (l15 == 0) {
                const int nl = mt * 16 + quad * 4 + r;
                sc_lds[wave][nl] = vs; dc_lds[wave][nl] = vd;
            }
        }
    for (int mt = 0; mt < 4; ++mt)
        for (int nt = 0; nt < 4; ++nt) {
            const int c = wave * 64 + nt * 16 + l15;
            const int n = mt * 16 + quad * 4;           // r in pairs (n..n+3)
            *(unsigned int*)&tr_lds[c * 72 + n] =
                cvtpk(acc[mt][nt][0], acc[mt][nt][1]);
            *(unsigned int*)&tr_lds[c * 72 + n + 2] =
                cvtpk(acc[mt][nt][2], acc[mt][nt][3]);
        }
    __syncthreads();
    if (t < 128) {
        const int n = t >> 1, h = t & 1;
        s[(size_t)(n0 + n) * 2 + h] = sc_lds[h * 2][n] + sc_lds[h * 2 + 1][n];
        d[(size_t)(n0 + n) * 2 + h] = dc_lds[h * 2][n] + dc_lds[h * 2 + 1][n];
    }
    for (int p = 0; p < 8; ++p) {
        const int idx = p * 256 + t;       // 2048 granules
        const int c = idx >> 3, g = idx & 7;
        *(b16x8*)(Tt + (size_t)c * NN + n0 + g * 8) = *(const b16x8*)&tr_lds[c * 72 + g * 8];
    }
}

// ---------------------------------------------------------------------------
// Kernel 2 (v6): v5 pipeline + VALU/latency trims.
//   - unroll-by-2 ping-pong (A/B reg sets): adj/d prefetch gets a FULL
//     iteration in flight before first use (no reg-copy-induced vmcnt stall)
//   - v_cvt_pk_bf16_f32 packs (8 instrs vs ~80), leaky via fmax
//   - all loop-invariant addresses hoisted (DMA src collapses to
//     tsrc0 + p*64*NN + jn; LDS offsets to afb/bfb + mt*1024 + X[ks])
//   Same barriers, same counted vmcnt(10), LDS 80KB -> 2 blocks/CU.
// ---------------------------------------------------------------------------
__global__ __launch_bounds__(512, 4) void k_gat(
    const int* __restrict__ adj, const unsigned short* __restrict__ Tt,
    const float* __restrict__ s, const float* __restrict__ d,
    float* __restrict__ num_part,   // [jsplit][NN][CD]
    float* __restrict__ den_part,   // [jsplit][2][NN]
    int jchunk)
{
    __shared__ unsigned short tt_lds[2][CD * BJ];    // 2 x 32KB
    __shared__ unsigned short w_lds[2 * BI * BJ];    // 16KB, XOR-swizzled

    const int t = threadIdx.x;
    const int w = t >> 6, lane = t & 63;
    const int l15 = lane & 15, quad = lane >> 4;
    const int h  = (w >> 2) & 1;    // head
    const int fh = (w >> 1) & 1;    // f-half
    const int rh = w & 1;           // row-half
    const int i0 = blockIdx.x * BI;
    const int chunk = blockIdx.y;
    const int jbase = chunk * jchunk;

    const int wi = t >> 3;          // 0..63 : row within i-tile
    const int j8 = t & 7;           // 0..7  : 8-wide j granule
    const int gi = i0 + wi;
    const float s0 = s[(size_t)gi * 2 + 0];
    const float s1 = s[(size_t)gi * 2 + 1];
    const int cbase = h * 128 + fh * 64;

    f32x4 acc[2][4] = {};
    float den0 = 0.f, den1 = 0.f;
    const int njt = jchunk / BJ;    // 32 (jsplit=4) or 64 -- always even

    // ---- hoisted addresses (all loop-invariant) ----
    const int* arow = adj + (size_t)gi * NN + j8 * 8;
    const float* drow = d + (size_t)j8 * 16;              // + 2*j at use
    // DMA: granule G=(p*8+w)*64+lane -> c = c0+p*64, g independent of p
    const int c0 = w * 8 + (lane >> 3);
    const int g0 = (lane & 7) ^ (c0 & 7);
    const unsigned short* tsrc0 = Tt + (size_t)c0 * NN + g0 * 8;
    const int toff0 = w * 1024;                           // + p*8192 bytes
    const int slot = (j8 ^ (wi & 7)) << 3;
    unsigned short* wp0 = &w_lds[(0 * BI + wi) * BJ + slot];
    // MFMA LDS offsets: af = afb + mt*1024 + X[ks]; bf = bfb + nt*1024 + X[ks]
    const int m0 = rh * 32 + l15;
    const int afb = (h * BI + m0) * BJ;
    const int bfb = (cbase + l15) * BJ;
    const int X0 = ((0 * 4 + quad) ^ (l15 & 7)) << 3;
    const int X1 = ((1 * 4 + quad) ^ (l15 & 7)) << 3;
    const int X[2] = {X0, X1};

    // ---- prologue: DMA tile0 -> buf0; prefetch adj/d(tile0) into A regs ----
    #pragma unroll
    for (int p = 0; p < 4; ++p)
        async16(tsrc0 + (size_t)p * 64 * NN + jbase,
                (char*)&tt_lds[0][0] + toff0 + p * 8192);
    int4 aA0 = *(const int4*)(arow + jbase);
    int4 aA1 = *(const int4*)(arow + jbase + 4);
    const float4* dpp = (const float4*)(drow + 2 * jbase);
    float4 dA0 = dpp[0], dA1 = dpp[1], dA2 = dpp[2], dA3 = dpp[3];
    int4 aB0, aB1; float4 dB0, dB1, dB2, dB3;

    auto body = [&](int jt, int buf,
                    int4& ca0, int4& ca1, float4& cd0, float4& cd1, float4& cd2, float4& cd3,
                    int4& na0, int4& na1, float4& nd0, float4& nd1, float4& nd2, float4& nd3) {
        const int j0 = jbase + jt * BJ;
        // all waves finished MFMA(jt-1) -> its tt buffer + w_lds are free
        __builtin_amdgcn_s_barrier();
        // stage NEXT tile into the released buffer
        const int jn = (jt + 1 < njt) ? j0 + BJ : j0;
        #pragma unroll
        for (int p = 0; p < 4; ++p)
            async16(tsrc0 + (size_t)p * 64 * NN + jn,
                    (char*)&tt_lds[buf ^ 1][0] + toff0 + p * 8192);
        // prefetch next adj + d into the OTHER reg set (consumed next body ->
        // full iteration of latency slack, no mid-iter wait)
        na0 = *(const int4*)(arow + jn);
        na1 = *(const int4*)(arow + jn + 4);
        { const float4* dnp = (const float4*)(drow + 2 * jn);
          nd0 = dnp[0]; nd1 = dnp[1]; nd2 = dnp[2]; nd3 = dnp[3]; }
        // exp weights for CURRENT tile (inputs loaded one full body ago)
        union { float4 v[4]; float f[16]; } dv;
        dv.v[0] = cd0; dv.v[1] = cd1; dv.v[2] = cd2; dv.v[3] = cd3;
        const int am[8] = {ca0.x, ca0.y, ca0.z, ca0.w, ca1.x, ca1.y, ca1.z, ca1.w};
        float e0f[8], e1f[8];
        float dp0 = 0.f, dp1 = 0.f;
        #pragma unroll
        for (int e = 0; e < 8; ++e) {
            float x0 = s0 + dv.f[e * 2 + 0];  x0 = fmaxf(x0, 0.2f * x0);
            float x1 = s1 + dv.f[e * 2 + 1];  x1 = fmaxf(x1, 0.2f * x1);
            e0f[e] = am[e] != 0 ? __expf(x0) : 0.f;
            e1f[e] = am[e] != 0 ? __expf(x1) : 0.f;
            dp0 += e0f[e]; dp1 += e1f[e];
        }
        den0 += dp0; den1 += dp1;
        union { unsigned int u[4]; b16x8 v; } w0, w1;
        #pragma unroll
        for (int q = 0; q < 4; ++q) {
            w0.u[q] = cvtpk(e0f[2 * q], e0f[2 * q + 1]);
            w1.u[q] = cvtpk(e1f[2 * q], e1f[2 * q + 1]);
        }
        *(b16x8*)wp0 = w0.v;
        *(b16x8*)(wp0 + BI * BJ) = w1.v;
        // COUNTED wait: 10 newer VMEM (4 DMA + 2 adj + 4 d, all for jt+1)
        // -> tile jt's DMAs certified landed; jt+1's stay in flight.
        asm volatile("s_waitcnt vmcnt(10) lgkmcnt(0)" ::: "memory");
        __builtin_amdgcn_s_barrier();
        __builtin_amdgcn_sched_barrier(0);
        // --- MFMA: num[i0+rh*32.., cbase..cbase+63] += w_h @ T ---
        #pragma unroll
        for (int ks = 0; ks < 2; ++ks) {
            b16x8 af[2], bf[4];
            #pragma unroll
            for (int mt = 0; mt < 2; ++mt)
                af[mt] = *(const b16x8*)&w_lds[afb + mt * 1024 + X[ks]];
            #pragma unroll
            for (int nt = 0; nt < 4; ++nt)
                bf[nt] = *(const b16x8*)&tt_lds[buf][bfb + nt * 1024 + X[ks]];
            #pragma unroll
            for (int mt = 0; mt < 2; ++mt)
                #pragma unroll
                for (int nt = 0; nt < 4; ++nt)
                    acc[mt][nt] = __builtin_amdgcn_mfma_f32_16x16x32_bf16(
                        af[mt], bf[nt], acc[mt][nt], 0, 0, 0);
        }
    };

    for (int jt = 0; jt < njt; jt += 2) {
        body(jt,     0, aA0, aA1, dA0, dA1, dA2, dA3, aB0, aB1, dB0, dB1, dB2, dB3);
        body(jt + 1, 1, aB0, aB1, dB0, dB1, dB2, dB3, aA0, aA1, dA0, dA1, dA2, dA3);
    }
    // drain tail DMAs before the wave retires / LDS is reallocated
    asm volatile("s_waitcnt vmcnt(0)" ::: "memory");
    // reduce den over the 8 j8-lanes (lane bits 0..2)
    den0 += __shfl_xor(den0, 1); den0 += __shfl_xor(den0, 2); den0 += __shfl_xor(den0, 4);
    den1 += __shfl_xor(den1, 1); den1 += __shfl_xor(den1, 2); den1 += __shfl_xor(den1, 4);
    if (j8 == 0) {
        den_part[((size_t)chunk * 2 + 0) * NN + gi] = den0;
        den_part[((size_t)chunk * 2 + 1) * NN + gi] = den1;
    }
    float* np_ = num_part + (size_t)chunk * NN * CD;
    for (int mt = 0; mt < 2; ++mt)
        for (int nt = 0; nt < 4; ++nt)
            for (int r = 0; r < 4; ++r) {
                const int n = i0 + rh * 32 + mt * 16 + quad * 4 + r;
                const int c = cbase + nt * 16 + l15;
                np_[(size_t)n * CD + c] = acc[mt][nt][r];
            }
}

// ---------------------------------------------------------------------------
// Kernel 3: combine partials, normalize, mean over heads.  grid=4096
// ---------------------------------------------------------------------------
__global__ __launch_bounds__(256) void k_combine(
    const float* __restrict__ num_part, const float* __restrict__ den_part,
    float* __restrict__ out, int jsplit)
{
    const int idx = blockIdx.x * 256 + threadIdx.x;   // NN*FD
    const int n = idx >> 7, f = idx & 127;
    const size_t row = (size_t)n * CD;
    float n0 = 0.f, n1 = 0.f, d0 = 0.f, d1 = 0.f;
    for (int c = 0; c < jsplit; ++c) {
        const size_t base = (size_t)c * NN * CD;
        n0 += num_part[base + row + f];
        n1 += num_part[base + row + 128 + f];
        d0 += den_part[((size_t)c * 2 + 0) * NN + n];
        d1 += den_part[((size_t)c * 2 + 1) * NN + n];
    }
    const float r0 = d0 != 0.f ? n0 / d0 : 0.f;
    const float r1 = d1 != 0.f ? n1 / d1 : 0.f;
    out[idx] = 0.5f * (r0 + r1);
}

// ---------------------------------------------------------------------------
extern "C" void kernel_launch(void* const* d_in, const int* in_sizes, int n_in,
                              void* d_out, int out_size, void* d_ws, size_t ws_size,
                              hipStream_t stream) {
    const float* feat = (const float*)d_in[0];
    const int*   adj  = (const int*)d_in[1];
    const float* W    = (const float*)d_in[2];
    const float* asrc = (const float*)d_in[3];
    const float* adst = (const float*)d_in[4];
    float* out = (float*)d_out;

    // jsplit=4 (40MB ws): grid 512 = exactly 2 blocks/CU, zero tail
    const int jsplit = (ws_size >= ((size_t)40 << 20)) ? 4 : 2;
    const int jchunk = NN / jsplit;

    char* ws = (char*)d_ws;
    unsigned short* Tt = (unsigned short*)ws;                       // 4 MB
    float* s    = (float*)(ws + ((size_t)4 << 20));                 // 64 KB
    float* dsc  = (float*)(ws + ((size_t)4 << 20) + (64 << 10));    // 64 KB
    float* den  = (float*)(ws + ((size_t)4 << 20) + (128 << 10));   // <=256 KB
    float* nump = (float*)(ws + ((size_t)8 << 20));                 // jsplit*8 MB

    k_transform<<<128, 256, 0, stream>>>(feat, W, asrc, adst, Tt, s, dsc);
    k_gat<<<dim3(NN / BI, jsplit), 512, 0, stream>>>(adj, Tt, s, dsc, nump, den, jchunk);
    k_combine<<<NN * FD / 256, 256, 0, stream>>>(nump, den, out, jsplit);
}

// Round 6
// 435.467 us; speedup vs baseline: 1.1926x; 1.0064x over previous
//
#include <hip/hip_runtime.h>
#include <stdint.h>
#include <stddef.h>

#define NN 8192      // nodes
#define KD 256       // in_dim
#define CD 256       // out_dim*heads
#define FD 128       // out_dim
#define BI 64        // i-tile rows per block (k_gat)
#define BJ 64        // j-tile
#define LOG2E 1.44269504f

typedef __attribute__((ext_vector_type(4))) float f32x4;
typedef __attribute__((ext_vector_type(2))) float f32x2;
typedef __attribute__((ext_vector_type(8))) short b16x8;

// pack two f32 -> two bf16 (RNE) in ONE instruction
__device__ __forceinline__ unsigned int cvtpk(float lo, float hi) {
    unsigned int r;
    asm("v_cvt_pk_bf16_f32 %0, %1, %2" : "=v"(r) : "v"(lo), "v"(hi));
    return r;
}

// raw 2^x (hardware transcendental); s_nop guards the trans-use window
__device__ __forceinline__ float exp2raw(float x) {
    float r;
    asm("v_exp_f32 %0, %1\n\ts_nop 0" : "=v"(r) : "v"(x));
    return r;
}

// async global->LDS, 16B per lane; lds dest = wave-uniform base + lane*16
__device__ __forceinline__ void async16(const void* g, void* l) {
    __builtin_amdgcn_global_load_lds(
        (const __attribute__((address_space(1))) unsigned int*)g,
        (__attribute__((address_space(3))) unsigned int*)l, 16, 0, 0);
}

// ---------------------------------------------------------------------------
// Kernel 1 (v7): 32-row blocks, grid=256 (was 128 -> only half the CUs).
//   Stores s,d PRE-SCALED by log2(e) (k_gat uses raw v_exp_f32 = 2^x;
//   leaky commutes with positive scaling).
// ---------------------------------------------------------------------------
__global__ __launch_bounds__(256) void k_transform(
    const float* __restrict__ feat, const float* __restrict__ W,
    const float* __restrict__ asrc, const float* __restrict__ adst,
    unsigned short* __restrict__ Tt, float* __restrict__ s, float* __restrict__ d)
{
    __shared__ unsigned short a_lds[32 * 32];    // 2KB
    __shared__ unsigned short b_lds[256 * 32];   // 16KB
    __shared__ unsigned short tr_lds[256 * 40];  // 20KB (stride 40 = 80B, 16B-aligned)
    __shared__ float sc_lds[4][32];              // .5KB
    __shared__ float dc_lds[4][32];              // .5KB

    const int t = threadIdx.x;
    const int wave = t >> 6, lane = t & 63;
    const int l15 = lane & 15, quad = lane >> 4;
    const int n0 = blockIdx.x * 32;

    f32x4 acc[2][4] = {};
    for (int kc = 0; kc < 8; ++kc) {
        const int k0 = kc * 32;
        __syncthreads();
        if (t < 128) { // stage A: features[n0+ai][k0 + ag*8 .. +7] -> bf16
            const int ai = t >> 2, ag = t & 3;
            const float* src = feat + (size_t)(n0 + ai) * KD + k0 + ag * 8;
            const float4 v0 = *(const float4*)src;
            const float4 v1 = *(const float4*)(src + 4);
            union { unsigned int u[4]; b16x8 v; } pk;
            pk.u[0] = cvtpk(v0.x, v0.y); pk.u[1] = cvtpk(v0.z, v0.w);
            pk.u[2] = cvtpk(v1.x, v1.y); pk.u[3] = cvtpk(v1.z, v1.w);
            const int slot = ag ^ ((ai >> 1) & 3);
            *(b16x8*)&a_lds[ai * 32 + slot * 8] = pk.v;
        }
        for (int p = 0; p < 4; ++p) { // stage B: W[c][k0 + g*8 .. +7]
            const int G = p * 256 + t;
            const int c = G >> 2, g = G & 3;
            const float* src = W + (size_t)c * KD + k0 + g * 8;
            const float4 v0 = *(const float4*)src;
            const float4 v1 = *(const float4*)(src + 4);
            union { unsigned int u[4]; b16x8 v; } pk;
            pk.u[0] = cvtpk(v0.x, v0.y); pk.u[1] = cvtpk(v0.z, v0.w);
            pk.u[2] = cvtpk(v1.x, v1.y); pk.u[3] = cvtpk(v1.z, v1.w);
            const int slot = g ^ ((c >> 1) & 3);
            *(b16x8*)&b_lds[c * 32 + slot * 8] = pk.v;
        }
        __syncthreads();
        b16x8 af[2], bfr[4];
        for (int mt = 0; mt < 2; ++mt) {
            const int m = mt * 16 + l15;
            af[mt] = *(const b16x8*)&a_lds[m * 32 + (quad ^ ((m >> 1) & 3)) * 8];
        }
        for (int nt = 0; nt < 4; ++nt) {
            const int c = wave * 64 + nt * 16 + l15;
            bfr[nt] = *(const b16x8*)&b_lds[c * 32 + (quad ^ ((c >> 1) & 3)) * 8];
        }
        for (int mt = 0; mt < 2; ++mt)
            for (int nt = 0; nt < 4; ++nt)
                acc[mt][nt] = __builtin_amdgcn_mfma_f32_16x16x32_bf16(
                    af[mt], bfr[nt], acc[mt][nt], 0, 0, 0);
    }

    // ---- epilogue: scores (fp32) + transposed bf16 store ----
    float aS[4], aD[4];
    for (int nt = 0; nt < 4; ++nt) {
        const int c = wave * 64 + nt * 16 + l15;
        aS[nt] = asrc[c]; aD[nt] = adst[c];
    }
    for (int mt = 0; mt < 2; ++mt)
        for (int r = 0; r < 4; ++r) {
            float vs = 0.f, vd = 0.f;
            for (int nt = 0; nt < 4; ++nt) {
                const float x = acc[mt][nt][r];
                vs += x * aS[nt]; vd += x * aD[nt];
            }
            vs += __shfl_xor(vs, 1); vd += __shfl_xor(vd, 1);
            vs += __shfl_xor(vs, 2); vd += __shfl_xor(vd, 2);
            vs += __shfl_xor(vs, 4); vd += __shfl_xor(vd, 4);
            vs += __shfl_xor(vs, 8); vd += __shfl_xor(vd, 8);
            if (l15 == 0) {
                const int nl = mt * 16 + quad * 4 + r;
                sc_lds[wave][nl] = vs; dc_lds[wave][nl] = vd;
            }
        }
    for (int mt = 0; mt < 2; ++mt)
        for (int nt = 0; nt < 4; ++nt) {
            const int c = wave * 64 + nt * 16 + l15;
            const int n = mt * 16 + quad * 4;           // r-pairs (n..n+3)
            *(unsigned int*)&tr_lds[c * 40 + n] =
                cvtpk(acc[mt][nt][0], acc[mt][nt][1]);
            *(unsigned int*)&tr_lds[c * 40 + n + 2] =
                cvtpk(acc[mt][nt][2], acc[mt][nt][3]);
        }
    __syncthreads();
    if (t < 64) {
        const int n = t >> 1, h = t & 1;
        // PRE-SCALED by log2e for k_gat's raw v_exp_f32 path
        s[(size_t)(n0 + n) * 2 + h] = (sc_lds[h * 2][n] + sc_lds[h * 2 + 1][n]) * LOG2E;
        d[(size_t)(n0 + n) * 2 + h] = (dc_lds[h * 2][n] + dc_lds[h * 2 + 1][n]) * LOG2E;
    }
    for (int p = 0; p < 4; ++p) {
        const int idx = p * 256 + t;       // 1024 granules (256 c x 4)
        const int c = idx >> 2, g = idx & 3;
        *(b16x8*)(Tt + (size_t)c * NN + n0 + g * 8) = *(const b16x8*)&tr_lds[c * 40 + g * 8];
    }
}

// ---------------------------------------------------------------------------
// Kernel 2 (v7): v6 pipeline (unchanged structure, counted vmcnt(10)) +
//   - exp phase as f32x2 head-pairs (d is [n][2]-interleaved -> natural
//     pairs; enables v_pk_add/max_f32), raw v_exp_f32 on pre-scaled scores
//   - s_setprio(1) around the MFMA cluster (T5: 2-phase + inter-block skew)
// ---------------------------------------------------------------------------
__global__ __launch_bounds__(512, 4) void k_gat(
    const int* __restrict__ adj, const unsigned short* __restrict__ Tt,
    const float* __restrict__ s, const float* __restrict__ d,
    float* __restrict__ num_part,   // [jsplit][NN][CD]
    float* __restrict__ den_part,   // [jsplit][2][NN]
    int jchunk)
{
    __shared__ unsigned short tt_lds[2][CD * BJ];    // 2 x 32KB
    __shared__ unsigned short w_lds[2 * BI * BJ];    // 16KB, XOR-swizzled

    const int t = threadIdx.x;
    const int w = t >> 6, lane = t & 63;
    const int l15 = lane & 15, quad = lane >> 4;
    const int h  = (w >> 2) & 1;    // head
    const int fh = (w >> 1) & 1;    // f-half
    const int rh = w & 1;           // row-half
    const int i0 = blockIdx.x * BI;
    const int chunk = blockIdx.y;
    const int jbase = chunk * jchunk;

    const int wi = t >> 3;          // 0..63 : row within i-tile
    const int j8 = t & 7;           // 0..7  : 8-wide j granule
    const int gi = i0 + wi;
    const f32x2 s01 = *(const f32x2*)(s + (size_t)gi * 2);   // pre-scaled
    const int cbase = h * 128 + fh * 64;

    f32x4 acc[2][4] = {};
    float den0 = 0.f, den1 = 0.f;
    const int njt = jchunk / BJ;    // 32 (jsplit=4) -- even

    // ---- hoisted addresses (all loop-invariant) ----
    const int* arow = adj + (size_t)gi * NN + j8 * 8;
    const float* drow = d + (size_t)j8 * 16;              // + 2*j at use
    const int c0 = w * 8 + (lane >> 3);
    const int g0 = (lane & 7) ^ (c0 & 7);
    const unsigned short* tsrc0 = Tt + (size_t)c0 * NN + g0 * 8;
    const int toff0 = w * 1024;                           // + p*8192 bytes
    const int slot = (j8 ^ (wi & 7)) << 3;
    unsigned short* wp0 = &w_lds[(0 * BI + wi) * BJ + slot];
    const int m0 = rh * 32 + l15;
    const int afb = (h * BI + m0) * BJ;
    const int bfb = (cbase + l15) * BJ;
    const int X[2] = {((0 * 4 + quad) ^ (l15 & 7)) << 3,
                      ((1 * 4 + quad) ^ (l15 & 7)) << 3};

    // ---- prologue: DMA tile0 -> buf0; prefetch adj/d(tile0) into A regs ----
    #pragma unroll
    for (int p = 0; p < 4; ++p)
        async16(tsrc0 + (size_t)p * 64 * NN + jbase,
                (char*)&tt_lds[0][0] + toff0 + p * 8192);
    int4 aA0 = *(const int4*)(arow + jbase);
    int4 aA1 = *(const int4*)(arow + jbase + 4);
    const float4* dpp = (const float4*)(drow + 2 * jbase);
    float4 dA0 = dpp[0], dA1 = dpp[1], dA2 = dpp[2], dA3 = dpp[3];
    int4 aB0, aB1; float4 dB0, dB1, dB2, dB3;

    auto body = [&](int jt, int buf,
                    int4& ca0, int4& ca1, float4& cd0, float4& cd1, float4& cd2, float4& cd3,
                    int4& na0, int4& na1, float4& nd0, float4& nd1, float4& nd2, float4& nd3) {
        const int j0 = jbase + jt * BJ;
        // all waves finished MFMA(jt-1) -> its tt buffer + w_lds are free
        __builtin_amdgcn_s_barrier();
        // stage NEXT tile into the released buffer
        const int jn = (jt + 1 < njt) ? j0 + BJ : j0;
        #pragma unroll
        for (int p = 0; p < 4; ++p)
            async16(tsrc0 + (size_t)p * 64 * NN + jn,
                    (char*)&tt_lds[buf ^ 1][0] + toff0 + p * 8192);
        // prefetch next adj + d into the OTHER reg set (full iter of slack)
        na0 = *(const int4*)(arow + jn);
        na1 = *(const int4*)(arow + jn + 4);
        { const float4* dnp = (const float4*)(drow + 2 * jn);
          nd0 = dnp[0]; nd1 = dnp[1]; nd2 = dnp[2]; nd3 = dnp[3]; }
        // exp weights for CURRENT tile, head-pairs as f32x2
        union { float4 v[4]; f32x2 p[8]; } dv;
        dv.v[0] = cd0; dv.v[1] = cd1; dv.v[2] = cd2; dv.v[3] = cd3;
        const int am[8] = {ca0.x, ca0.y, ca0.z, ca0.w, ca1.x, ca1.y, ca1.z, ca1.w};
        f32x2 ef[8];
        f32x2 dp = {0.f, 0.f};
        #pragma unroll
        for (int e = 0; e < 8; ++e) {
            const f32x2 x = s01 + dv.p[e];
            const f32x2 xm = __builtin_elementwise_max(x, 0.2f * x);
            const float r0 = exp2raw(xm.x), r1 = exp2raw(xm.y);
            const f32x2 em = {am[e] != 0 ? r0 : 0.f, am[e] != 0 ? r1 : 0.f};
            ef[e] = em; dp += em;
        }
        den0 += dp.x; den1 += dp.y;
        union { unsigned int u[4]; b16x8 v; } w0, w1;
        #pragma unroll
        for (int q = 0; q < 4; ++q) {
            w0.u[q] = cvtpk(ef[2 * q].x, ef[2 * q + 1].x);
            w1.u[q] = cvtpk(ef[2 * q].y, ef[2 * q + 1].y);
        }
        *(b16x8*)wp0 = w0.v;
        *(b16x8*)(wp0 + BI * BJ) = w1.v;
        // COUNTED wait: 10 newer VMEM (4 DMA + 2 adj + 4 d, all for jt+1)
        asm volatile("s_waitcnt vmcnt(10) lgkmcnt(0)" ::: "memory");
        __builtin_amdgcn_s_barrier();
        __builtin_amdgcn_sched_barrier(0);
        // --- MFMA: num[i0+rh*32.., cbase..cbase+63] += w_h @ T ---
        __builtin_amdgcn_s_setprio(1);
        #pragma unroll
        for (int ks = 0; ks < 2; ++ks) {
            b16x8 af[2], bf[4];
            #pragma unroll
            for (int mt = 0; mt < 2; ++mt)
                af[mt] = *(const b16x8*)&w_lds[afb + mt * 1024 + X[ks]];
            #pragma unroll
            for (int nt = 0; nt < 4; ++nt)
                bf[nt] = *(const b16x8*)&tt_lds[buf][bfb + nt * 1024 + X[ks]];
            #pragma unroll
            for (int mt = 0; mt < 2; ++mt)
                #pragma unroll
                for (int nt = 0; nt < 4; ++nt)
                    acc[mt][nt] = __builtin_amdgcn_mfma_f32_16x16x32_bf16(
                        af[mt], bf[nt], acc[mt][nt], 0, 0, 0);
        }
        __builtin_amdgcn_s_setprio(0);
    };

    for (int jt = 0; jt < njt; jt += 2) {
        body(jt,     0, aA0, aA1, dA0, dA1, dA2, dA3, aB0, aB1, dB0, dB1, dB2, dB3);
        body(jt + 1, 1, aB0, aB1, dB0, dB1, dB2, dB3, aA0, aA1, dA0, dA1, dA2, dA3);
    }
    // drain tail DMAs before the wave retires / LDS is reallocated
    asm volatile("s_waitcnt vmcnt(0)" ::: "memory");
    // reduce den over the 8 j8-lanes (lane bits 0..2)
    den0 += __shfl_xor(den0, 1); den0 += __shfl_xor(den0, 2); den0 += __shfl_xor(den0, 4);
    den1 += __shfl_xor(den1, 1); den1 += __shfl_xor(den1, 2); den1 += __shfl_xor(den1, 4);
    if (j8 == 0) {
        den_part[((size_t)chunk * 2 + 0) * NN + gi] = den0;
        den_part[((size_t)chunk * 2 + 1) * NN + gi] = den1;
    }
    float* np_ = num_part + (size_t)chunk * NN * CD;
    for (int mt = 0; mt < 2; ++mt)
        for (int nt = 0; nt < 4; ++nt)
            for (int r = 0; r < 4; ++r) {
                const int n = i0 + rh * 32 + mt * 16 + quad * 4 + r;
                const int c = cbase + nt * 16 + l15;
                np_[(size_t)n * CD + c] = acc[mt][nt][r];
            }
}

// ---------------------------------------------------------------------------
// Kernel 3: combine partials, normalize, mean over heads.  grid=4096
// ---------------------------------------------------------------------------
__global__ __launch_bounds__(256) void k_combine(
    const float* __restrict__ num_part, const float* __restrict__ den_part,
    float* __restrict__ out, int jsplit)
{
    const int idx = blockIdx.x * 256 + threadIdx.x;   // NN*FD
    const int n = idx >> 7, f = idx & 127;
    const size_t row = (size_t)n * CD;
    float n0 = 0.f, n1 = 0.f, d0 = 0.f, d1 = 0.f;
    for (int c = 0; c < jsplit; ++c) {
        const size_t base = (size_t)c * NN * CD;
        n0 += num_part[base + row + f];
        n1 += num_part[base + row + 128 + f];
        d0 += den_part[((size_t)c * 2 + 0) * NN + n];
        d1 += den_part[((size_t)c * 2 + 1) * NN + n];
    }
    const float r0 = d0 != 0.f ? n0 / d0 : 0.f;
    const float r1 = d1 != 0.f ? n1 / d1 : 0.f;
    out[idx] = 0.5f * (r0 + r1);
}

// ---------------------------------------------------------------------------
extern "C" void kernel_launch(void* const* d_in, const int* in_sizes, int n_in,
                              void* d_out, int out_size, void* d_ws, size_t ws_size,
                              hipStream_t stream) {
    const float* feat = (const float*)d_in[0];
    const int*   adj  = (const int*)d_in[1];
    const float* W    = (const float*)d_in[2];
    const float* asrc = (const float*)d_in[3];
    const float* adst = (const float*)d_in[4];
    float* out = (float*)d_out;

    // jsplit=4 (40MB ws): grid 512 = exactly 2 blocks/CU, zero tail
    const int jsplit = (ws_size >= ((size_t)40 << 20)) ? 4 : 2;
    const int jchunk = NN / jsplit;

    char* ws = (char*)d_ws;
    unsigned short* Tt = (unsigned short*)ws;                       // 4 MB
    float* s    = (float*)(ws + ((size_t)4 << 20));                 // 64 KB
    float* dsc  = (float*)(ws + ((size_t)4 << 20) + (64 << 10));    // 64 KB
    float* den  = (float*)(ws + ((size_t)4 << 20) + (128 << 10));   // <=256 KB
    float* nump = (float*)(ws + ((size_t)8 << 20));                 // jsplit*8 MB

    k_transform<<<256, 256, 0, stream>>>(feat, W, asrc, adst, Tt, s, dsc);
    k_gat<<<dim3(NN / BI, jsplit), 512, 0, stream>>>(adj, Tt, s, dsc, nump, den, jchunk);
    k_combine<<<NN * FD / 256, 256, 0, stream>>>(nump, den, out, jsplit);
}